// Round 1
// baseline (31136.853 us; speedup 1.0000x reference)
//
#include <hip/hip_runtime.h>

// Persistent wavefront-pipelined LSTMP (3 layers), split-bf16 MFMA emulating fp32.
// Grid = 256 blocks x 256 threads, all co-resident (10KB LDS, modest VGPR).
// Layer l processes t = s - l at global step s; 2 grid barriers per step.

typedef short s16x8 __attribute__((ext_vector_type(8)));
typedef float f32x4 __attribute__((ext_vector_type(4)));

#define MFMA16(a,b,c) __builtin_amdgcn_mfma_f32_16x16x32_bf16((a),(b),(c),0,0,0)

__device__ __forceinline__ unsigned short f2bf(float f) {
  unsigned int u = __builtin_bit_cast(unsigned int, f);
  u += 0x7FFFu + ((u >> 16) & 1u);          // RNE
  return (unsigned short)(u >> 16);
}
__device__ __forceinline__ float bf2f(unsigned short h) {
  unsigned int u = ((unsigned int)h) << 16;
  return __builtin_bit_cast(float, u);
}
__device__ __forceinline__ float fsig(float x)  { return __fdividef(1.0f, 1.0f + __expf(-x)); }
__device__ __forceinline__ float ftanh(float x) { return 1.0f - __fdividef(2.0f, 1.0f + __expf(2.0f * x)); }

// Sense-counting grid barrier. Slots/release live in ws (0xAA-poisoned each launch);
// equality against monotone seq (1,2,3,...) makes garbage harmless.
__device__ __forceinline__ void grid_barrier(unsigned int* bar, unsigned int* rel, unsigned int seq) {
  __syncthreads();  // compiler emits vmcnt(0) drain before s_barrier -> block stores are in L2
  const int tid = threadIdx.x;
  const int bid = blockIdx.x;
  if (bid == 0) {
    if (tid >= 1 && tid < 256) {
      while (__hip_atomic_load(&bar[tid * 16], __ATOMIC_RELAXED, __HIP_MEMORY_SCOPE_AGENT) != seq) {
        __builtin_amdgcn_s_sleep(2);
      }
    }
    __syncthreads();
    if (tid == 0) {
      __hip_atomic_store(rel, seq, __ATOMIC_RELEASE, __HIP_MEMORY_SCOPE_AGENT);
    }
  } else {
    if (tid == 0) {
      __hip_atomic_store(&bar[bid * 16], seq, __ATOMIC_RELEASE, __HIP_MEMORY_SCOPE_AGENT);
      while (__hip_atomic_load(rel, __ATOMIC_RELAXED, __HIP_MEMORY_SCOPE_AGENT) != seq) {
        __builtin_amdgcn_s_sleep(2);
      }
    }
    __syncthreads();
  }
  __builtin_amdgcn_fence(__ATOMIC_ACQUIRE, "agent");
}

__global__ __launch_bounds__(256, 1) void lstmp_persist(
    const float* __restrict__ x,
    const float* __restrict__ W0, const float* __restrict__ b0, const float* __restrict__ P0,
    const float* __restrict__ pi0, const float* __restrict__ pf0, const float* __restrict__ po0,
    const float* __restrict__ W1, const float* __restrict__ b1, const float* __restrict__ P1,
    const float* __restrict__ pi1, const float* __restrict__ pf1, const float* __restrict__ po1,
    const float* __restrict__ W2, const float* __restrict__ b2, const float* __restrict__ P2,
    const float* __restrict__ pi2, const float* __restrict__ pf2, const float* __restrict__ po2,
    float* __restrict__ out, unsigned char* __restrict__ ws)
{
  const int tid  = threadIdx.x;
  const int bid  = blockIdx.x;
  const int lane = tid & 63;
  const int wv   = tid >> 6;
  const int quad8 = (lane >> 4) * 8;   // k-offset within 32-k block for this lane
  const int nrow  = lane & 15;         // row-within-16-tile for A/B fragments

  // ---- workspace carve (bytes -> typed) ----
  unsigned int* bar = (unsigned int*)ws;          // 256 slots * 16 uints
  unsigned int* rel = bar + 4096;
  unsigned short* xhi = (unsigned short*)(ws + 20480);
  unsigned short* xlo  = xhi  + 4096000;   // 500*32*256
  unsigned short* hhi  = xlo  + 4096000;   // 3*32*512
  unsigned short* hlo  = hhi  + 49152;
  unsigned short* mhi  = hlo  + 49152;     // 3*32*1024
  unsigned short* mlo  = mhi  + 98304;
  unsigned short* wBh0 = mlo  + 98304;     // 256*24*512
  unsigned short* wBl0 = wBh0 + 3145728;
  unsigned short* wBh1 = wBl0 + 3145728;   // 256*32*512
  unsigned short* wBl1 = wBh1 + 4194304;
  unsigned short* wBh2 = wBl1 + 4194304;
  unsigned short* wBl2 = wBh2 + 4194304;
  unsigned short* wPh  = wBl2 + 4194304;   // 3 * 32*32*512
  unsigned short* wPl  = wPh  + 1572864;

  const float* Wsrc[3] = {W0, W1, W2};
  const float* Psrc[3] = {P0, P1, P2};
  const float* Bsrc[3] = {b0, b1, b2};
  const float* PIs[3]  = {pi0, pi1, pi2};
  const float* PFs[3]  = {pf0, pf1, pf2};
  const float* POs[3]  = {po0, po1, po2};
  unsigned short* wBhv[3] = {wBh0, wBh1, wBh2};
  unsigned short* wBlv[3] = {wBl0, wBl1, wBl2};
  const int NKBv[3]    = {24, 32, 32};   // K_pad/32
  const int NKBINv[3]  = {8, 16, 16};    // input-region k-blocks
  const int KINPADv[3] = {256, 512, 512};
  const int KWv[3]     = {752, 1024, 1024};
  const int NINv[3]    = {240, 512, 512};

  __shared__ float exch[4][512];   // [wave][m*16+col]; reused as [wave][256] in proj reduce
  __shared__ float c_lds[512];     // persistent cell state: [b*16 + u]

  const unsigned int gtid = (unsigned int)bid * 256u + (unsigned int)tid;

  // ================= INIT (every launch; ws is re-poisoned) =================
  // x -> hi/lo bf16 planes, zero-padded 240 -> 256 columns
  for (unsigned int i = gtid; i < 4096000u; i += 65536u) {
    unsigned int k = i & 255u, tb = i >> 8;
    float v = (k < 240u) ? x[tb * 240u + k] : 0.0f;
    unsigned short h = f2bf(v);
    xhi[i] = h; xlo[i] = f2bf(v - bf2f(h));
  }
  // h planes zero (h0 = 0)
  for (unsigned int i = gtid; i < 49152u; i += 65536u) { hhi[i] = 0; hlo[i] = 0; }
  // gate-weight streams, MFMA B-fragment order: ((gt*NKB + kb)*64 + lane)*8 + j
  for (int l = 0; l < 3; ++l) {
    const unsigned int nkb = (unsigned int)NKBv[l];
    const unsigned int tot = 256u * nkb * 512u;
    const float* Wl = Wsrc[l];
    unsigned short* dh = wBhv[l];
    unsigned short* dl = wBlv[l];
    const int kinpad = KINPADv[l], kw = KWv[l], nin = NINv[l];
    for (unsigned int i = gtid; i < tot; i += 65536u) {
      unsigned int j  = i & 7u;
      unsigned int ln = (i >> 3) & 63u;
      unsigned int kb = (i >> 9) % nkb;
      unsigned int gt = i / (nkb * 512u);
      unsigned int g  = gt * 16u + (ln & 15u);
      int k = (int)(kb * 32u + ((ln >> 4) * 8u) + j);
      float v;
      if (k < kinpad) v = (l == 0 && k >= 240) ? 0.0f : Wl[(size_t)g * kw + k];
      else            v = Wl[(size_t)g * kw + (k - kinpad + nin)];
      unsigned short h = f2bf(v);
      dh[i] = h; dl[i] = f2bf(v - bf2f(h));
    }
  }
  // projection streams
  for (int l = 0; l < 3; ++l) {
    const float* Pl = Psrc[l];
    unsigned short* dh = wPh + (size_t)l * 524288u;
    unsigned short* dl = wPl + (size_t)l * 524288u;
    for (unsigned int i = gtid; i < 524288u; i += 65536u) {
      unsigned int j  = i & 7u;
      unsigned int ln = (i >> 3) & 63u;
      unsigned int kb = (i >> 9) & 31u;
      unsigned int pt = i >> 14;
      unsigned int prow = pt * 16u + (ln & 15u);
      int k = (int)(kb * 32u + ((ln >> 4) * 8u) + j);
      float v = Pl[(size_t)prow * 1024u + k];
      unsigned short h = f2bf(v);
      dh[i] = h; dl[i] = f2bf(v - bf2f(h));
    }
  }
  c_lds[tid] = 0.0f; c_lds[tid + 256] = 0.0f;

  unsigned int seq = 1;
  grid_barrier(bar, rel, seq++);

  // ---- fixed per-block roles ----
  const bool worker = (bid < 192);
  const int lA  = bid >> 6;          // layer (phase A and phase C)
  const int utA = bid & 63;          // 16-unit tile (phase A)
  const int ptC = (bid & 63) >> 1;   // proj 16-col tile (phase C)
  const int mtC = bid & 1;           // batch half (phase C)

  const int nkb    = NKBv[lA & 3 ? lA : lA];  // (lA in [0,3))
  const int nkbA   = NKBv[lA];
  const int nkbinA = NKBINv[lA];
  const int kinpadA = KINPADv[lA];
  (void)nkb;

  for (int s = 0; s < 502; ++s) {
    const int t = s - lA;
    const bool act = worker && (t >= 0) && (t < 500);

    // ================= PHASE A: gates GEMM + pointwise =================
    if (act) {
      const int gt = wv * 64 + utA;  // wave w handles gate section w (c_in,i,f,o)
      const unsigned short* bhp = wBhv[lA] + ((size_t)gt * nkbA) * 512 + lane * 8;
      const unsigned short* blp = wBlv[lA] + ((size_t)gt * nkbA) * 512 + lane * 8;
      f32x4 acc0 = {0.f,0.f,0.f,0.f}, acc1 = {0.f,0.f,0.f,0.f};

      const unsigned short *iah, *ial;
      int istride;
      if (lA == 0) {
        iah = xhi + (size_t)(t * 32 + nrow) * 256;
        ial = xlo + (size_t)(t * 32 + nrow) * 256;
        istride = 256;
      } else {
        iah = hhi + (size_t)((lA - 1) * 32 + nrow) * 512;
        ial = hlo + (size_t)((lA - 1) * 32 + nrow) * 512;
        istride = 512;
      }
      // region 1: input part (x or h_{l-1}[t])
      for (int kb = 0; kb < nkbinA; ++kb) {
        const int ko = kb * 32 + quad8;
        s16x8 fa0h = *(const s16x8*)(iah + ko);
        s16x8 fa0l = *(const s16x8*)(ial + ko);
        s16x8 fa1h = *(const s16x8*)(iah + 16 * istride + ko);
        s16x8 fa1l = *(const s16x8*)(ial + 16 * istride + ko);
        s16x8 fbh  = *(const s16x8*)(bhp + (size_t)kb * 512);
        s16x8 fbl  = *(const s16x8*)(blp + (size_t)kb * 512);
        acc0 = MFMA16(fa0h, fbh, acc0);
        acc0 = MFMA16(fa0l, fbh, acc0);
        acc0 = MFMA16(fa0h, fbl, acc0);
        acc1 = MFMA16(fa1h, fbh, acc1);
        acc1 = MFMA16(fa1l, fbh, acc1);
        acc1 = MFMA16(fa1h, fbl, acc1);
      }
      // region 2: recurrent part (h_l[t-1])
      {
        const unsigned short* hah = hhi + (size_t)(lA * 32 + nrow) * 512;
        const unsigned short* hal = hlo + (size_t)(lA * 32 + nrow) * 512;
        for (int kb = nkbinA; kb < nkbA; ++kb) {
          const int ko = kb * 32 + quad8 - kinpadA;
          s16x8 fa0h = *(const s16x8*)(hah + ko);
          s16x8 fa0l = *(const s16x8*)(hal + ko);
          s16x8 fa1h = *(const s16x8*)(hah + 16 * 512 + ko);
          s16x8 fa1l = *(const s16x8*)(hal + 16 * 512 + ko);
          s16x8 fbh  = *(const s16x8*)(bhp + (size_t)kb * 512);
          s16x8 fbl  = *(const s16x8*)(blp + (size_t)kb * 512);
          acc0 = MFMA16(fa0h, fbh, acc0);
          acc0 = MFMA16(fa0l, fbh, acc0);
          acc0 = MFMA16(fa0h, fbl, acc0);
          acc1 = MFMA16(fa1h, fbh, acc1);
          acc1 = MFMA16(fa1l, fbh, acc1);
          acc1 = MFMA16(fa1h, fbl, acc1);
        }
      }
      // dump C-frags to LDS: exch[gate][b*16+u]   (C layout: col=lane&15, row=quad*4+reg)
      #pragma unroll
      for (int r = 0; r < 4; ++r) {
        const int m0 = (lane >> 4) * 4 + r;
        exch[wv][m0 * 16 + (lane & 15)]        = acc0[r];
        exch[wv][(m0 + 16) * 16 + (lane & 15)] = acc1[r];
      }
      __syncthreads();

      // fused pointwise: each thread handles 2 (b,u) elements; c persists in LDS
      const float* bias = Bsrc[lA];
      const float* piv  = PIs[lA];
      const float* pfv  = PFs[lA];
      const float* pov  = POs[lA];
      for (int e = tid; e < 512; e += 256) {
        const int b = e >> 4, u = e & 15;
        const int uc = utA * 16 + u;
        const float cin = exch[0][e] + bias[uc];
        const float gi  = exch[1][e] + bias[1024 + uc];
        const float gf  = exch[2][e] + bias[2048 + uc];
        const float go  = exch[3][e] + bias[3072 + uc];
        const float cx  = c_lds[e];
        const float ig  = fsig(gi + piv[uc] * cx);
        const float fg  = fsig(gf + pfv[uc] * cx);
        float cy = fg * cx + ig * ftanh(cin);
        cy = fminf(50.0f, fmaxf(-50.0f, cy));
        const float og = fsig(go + pov[uc] * cy);
        const float mv = og * ftanh(cy);
        c_lds[e] = cy;
        const size_t mi = (size_t)(lA * 32 + b) * 1024 + uc;
        const unsigned short mh = f2bf(mv);
        mhi[mi] = mh;
        mlo[mi] = f2bf(mv - bf2f(mh));
      }
    }
    grid_barrier(bar, rel, seq++);

    // ================= PHASE C: projection + h/out write =================
    if (act) {
      const unsigned short* pph = wPh + (size_t)lA * 524288 + ((size_t)ptC * 32) * 512 + lane * 8;
      const unsigned short* ppl = wPl + (size_t)lA * 524288 + ((size_t)ptC * 32) * 512 + lane * 8;
      const unsigned short* mah = mhi + (size_t)(lA * 32 + mtC * 16 + nrow) * 1024;
      const unsigned short* mal = mlo + (size_t)(lA * 32 + mtC * 16 + nrow) * 1024;
      f32x4 acc = {0.f,0.f,0.f,0.f};
      // each wave covers 8 of 32 k-blocks (K-split), partials reduced via LDS
      for (int kb = wv * 8; kb < wv * 8 + 8; ++kb) {
        const int ko = kb * 32 + quad8;
        s16x8 fah = *(const s16x8*)(mah + ko);
        s16x8 fal = *(const s16x8*)(mal + ko);
        s16x8 fbh = *(const s16x8*)(pph + (size_t)kb * 512);
        s16x8 fbl = *(const s16x8*)(ppl + (size_t)kb * 512);
        acc = MFMA16(fah, fbh, acc);
        acc = MFMA16(fal, fbh, acc);
        acc = MFMA16(fah, fbl, acc);
      }
      #pragma unroll
      for (int r = 0; r < 4; ++r) {
        exch[wv][((lane >> 4) * 4 + r) * 16 + (lane & 15)] = acc[r];
      }
      __syncthreads();
      {
        const float v = exch[0][tid] + exch[1][tid] + exch[2][tid] + exch[3][tid];
        const int b = mtC * 16 + (tid >> 4);
        const int p = ptC * 16 + (tid & 15);
        const size_t hidx = (size_t)(lA * 32 + b) * 512 + p;
        const unsigned short hh = f2bf(v);
        hhi[hidx] = hh;
        hlo[hidx] = f2bf(v - bf2f(hh));
        if (lA == 2) out[((size_t)t * 32 + b) * 512 + p] = v;
      }
    }
    grid_barrier(bar, rel, seq++);
  }
}

extern "C" void kernel_launch(void* const* d_in, const int* in_sizes, int n_in,
                              void* d_out, int out_size, void* d_ws, size_t ws_size,
                              hipStream_t stream) {
  const float* x   = (const float*)d_in[0];
  const float* W0  = (const float*)d_in[1];
  const float* b0  = (const float*)d_in[2];
  const float* P0  = (const float*)d_in[3];
  const float* pi0 = (const float*)d_in[4];
  const float* pf0 = (const float*)d_in[5];
  const float* po0 = (const float*)d_in[6];
  const float* W1  = (const float*)d_in[7];
  const float* b1  = (const float*)d_in[8];
  const float* P1  = (const float*)d_in[9];
  const float* pi1 = (const float*)d_in[10];
  const float* pf1 = (const float*)d_in[11];
  const float* po1 = (const float*)d_in[12];
  const float* W2  = (const float*)d_in[13];
  const float* b2  = (const float*)d_in[14];
  const float* P2  = (const float*)d_in[15];
  const float* pi2 = (const float*)d_in[16];
  const float* pf2 = (const float*)d_in[17];
  const float* po2 = (const float*)d_in[18];

  hipLaunchKernelGGL(lstmp_persist, dim3(256), dim3(256), 0, stream,
                     x, W0, b0, P0, pi0, pf0, po0,
                     W1, b1, P1, pi1, pf1, po1,
                     W2, b2, P2, pi2, pf2, po2,
                     (float*)d_out, (unsigned char*)d_ws);
}

// Round 3
// 12740.104 us; speedup vs baseline: 2.4440x; 2.4440x over previous
//
#include <hip/hip_runtime.h>

// Persistent wavefront-pipelined LSTMP (3 layers), split-bf16 MFMA emulating fp32.
// Round 3: fix LDS overflow (exch[4][4][512]) that clobbered c_lds cell state.
// Relaxed-atomic grid barrier (no per-step L2 invalidation); cross-block h/m via
// relaxed agent-scope atomics (LIC-coherent); waves split K; weights stay hot in
// L1/L2 via plain cached loads.

typedef short s16x4 __attribute__((ext_vector_type(4)));
typedef short s16x8 __attribute__((ext_vector_type(8)));
typedef float f32x4 __attribute__((ext_vector_type(4)));

#define MFMA16(a,b,c) __builtin_amdgcn_mfma_f32_16x16x32_bf16((a),(b),(c),0,0,0)

__device__ __forceinline__ unsigned short f2bf(float f) {
  unsigned int u = __builtin_bit_cast(unsigned int, f);
  u += 0x7FFFu + ((u >> 16) & 1u);          // RNE
  return (unsigned short)(u >> 16);
}
__device__ __forceinline__ float bf2f(unsigned short h) {
  unsigned int u = ((unsigned int)h) << 16;
  return __builtin_bit_cast(float, u);
}
__device__ __forceinline__ float fsig(float x)  { return __fdividef(1.0f, 1.0f + __expf(-x)); }
__device__ __forceinline__ float ftanh(float x) { return 1.0f - __fdividef(2.0f, 1.0f + __expf(2.0f * x)); }

// Coherent (LIC) 16B read as two relaxed agent-scope 8B atomic loads.
__device__ __forceinline__ s16x8 cload(const unsigned short* p) {
  unsigned long long a = __hip_atomic_load((unsigned long long*)p,       __ATOMIC_RELAXED, __HIP_MEMORY_SCOPE_AGENT);
  unsigned long long b = __hip_atomic_load((unsigned long long*)(p + 4), __ATOMIC_RELAXED, __HIP_MEMORY_SCOPE_AGENT);
  s16x4 x = __builtin_bit_cast(s16x4, a);
  s16x4 y = __builtin_bit_cast(s16x4, b);
  s16x8 r = {x[0], x[1], x[2], x[3], y[0], y[1], y[2], y[3]};
  return r;
}
// Coherent 4B store (two packed shorts).
__device__ __forceinline__ void cstore2(unsigned short* p, unsigned short a, unsigned short b) {
  unsigned int v = (unsigned int)a | ((unsigned int)b << 16);
  __hip_atomic_store((unsigned int*)p, v, __ATOMIC_RELAXED, __HIP_MEMORY_SCOPE_AGENT);
}

// Relaxed sense-counting grid barrier: NO fences, NO cache maintenance.
// __syncthreads() drains vmcnt (stores complete at LIC) before arrival store.
__device__ __forceinline__ void gbar(unsigned int* bar, unsigned int* rel, unsigned int seq) {
  __syncthreads();
  asm volatile("" ::: "memory");
  if (blockIdx.x == 0) {
    const int tid = threadIdx.x;
    if (tid > 0) {
      while (__hip_atomic_load(&bar[tid * 16], __ATOMIC_RELAXED, __HIP_MEMORY_SCOPE_AGENT) != seq) {
        __builtin_amdgcn_s_sleep(1);
      }
    }
    __syncthreads();
    if (tid == 0) {
      __hip_atomic_store(rel, seq, __ATOMIC_RELAXED, __HIP_MEMORY_SCOPE_AGENT);
    }
  } else {
    if (threadIdx.x == 0) {
      __hip_atomic_store(&bar[blockIdx.x * 16], seq, __ATOMIC_RELAXED, __HIP_MEMORY_SCOPE_AGENT);
      while (__hip_atomic_load(rel, __ATOMIC_RELAXED, __HIP_MEMORY_SCOPE_AGENT) != seq) {
        __builtin_amdgcn_s_sleep(1);
      }
    }
    __syncthreads();
  }
  asm volatile("" ::: "memory");
}

__global__ __launch_bounds__(256, 1) void lstmp_persist(
    const float* __restrict__ x,
    const float* __restrict__ W0, const float* __restrict__ b0, const float* __restrict__ P0,
    const float* __restrict__ pi0, const float* __restrict__ pf0, const float* __restrict__ po0,
    const float* __restrict__ W1, const float* __restrict__ b1, const float* __restrict__ P1,
    const float* __restrict__ pi1, const float* __restrict__ pf1, const float* __restrict__ po1,
    const float* __restrict__ W2, const float* __restrict__ b2, const float* __restrict__ P2,
    const float* __restrict__ pi2, const float* __restrict__ pf2, const float* __restrict__ po2,
    float* __restrict__ out, unsigned char* __restrict__ ws)
{
  const int tid  = threadIdx.x;
  const int bid  = blockIdx.x;
  const int lane = tid & 63;
  const int wv   = tid >> 6;
  const int quad8 = (lane >> 4) * 8;   // k-offset within 32-k block for this lane
  const int nrow  = lane & 15;         // row-within-16-tile for A/B fragments

  // ---- workspace carve ----
  unsigned int* bar = (unsigned int*)ws;          // 256 slots * 16 uints
  unsigned int* rel = bar + 4096;
  unsigned short* xhi = (unsigned short*)(ws + 20480);
  unsigned short* xlo  = xhi  + 4096000;   // 500*32*256
  unsigned short* hhi  = xlo  + 4096000;   // 3*32*512
  unsigned short* hlo  = hhi  + 49152;
  unsigned short* mhi  = hlo  + 49152;     // 3*32*1024
  unsigned short* mlo  = mhi  + 98304;
  unsigned short* wBh0 = mlo  + 98304;     // 256*24*512
  unsigned short* wBl0 = wBh0 + 3145728;
  unsigned short* wBh1 = wBl0 + 3145728;   // 256*32*512
  unsigned short* wBl1 = wBh1 + 4194304;
  unsigned short* wBh2 = wBl1 + 4194304;
  unsigned short* wBl2 = wBh2 + 4194304;
  unsigned short* wPh  = wBl2 + 4194304;   // 3 * 32*32*512
  unsigned short* wPl  = wPh  + 1572864;

  const float* Wsrc[3] = {W0, W1, W2};
  const float* Psrc[3] = {P0, P1, P2};
  const float* Bsrc[3] = {b0, b1, b2};
  const float* PIs[3]  = {pi0, pi1, pi2};
  const float* PFs[3]  = {pf0, pf1, pf2};
  const float* POs[3]  = {po0, po1, po2};
  unsigned short* wBhv[3] = {wBh0, wBh1, wBh2};
  unsigned short* wBlv[3] = {wBl0, wBl1, wBl2};
  const int NKBv[3]    = {24, 32, 32};   // K_pad/32
  const int NKBINv[3]  = {8, 16, 16};    // input-region k-blocks
  const int KINPADv[3] = {256, 512, 512};
  const int KWv[3]     = {752, 1024, 1024};
  const int NINv[3]    = {240, 512, 512};

  __shared__ float exch[4][4][512];  // [wave][gate][b*16+u] partial sums (b in 0..31!)
  __shared__ float c_lds[512];       // persistent cell state: [b*16 + u]

  const unsigned int gtid = (unsigned int)bid * 256u + (unsigned int)tid;

  // ================= INIT (every launch; ws is re-poisoned) =================
  for (unsigned int i = gtid; i < 4096000u; i += 65536u) {
    unsigned int k = i & 255u, tb = i >> 8;
    float v = (k < 240u) ? x[tb * 240u + k] : 0.0f;
    unsigned short h = f2bf(v);
    xhi[i] = h; xlo[i] = f2bf(v - bf2f(h));
  }
  for (unsigned int i = gtid; i < 49152u; i += 65536u) { hhi[i] = 0; hlo[i] = 0; }
  for (int l = 0; l < 3; ++l) {
    const unsigned int nkb = (unsigned int)NKBv[l];
    const unsigned int tot = 256u * nkb * 512u;
    const float* Wl = Wsrc[l];
    unsigned short* dh = wBhv[l];
    unsigned short* dl = wBlv[l];
    const int kinpad = KINPADv[l], kw = KWv[l], nin = NINv[l];
    for (unsigned int i = gtid; i < tot; i += 65536u) {
      unsigned int j  = i & 7u;
      unsigned int ln = (i >> 3) & 63u;
      unsigned int kb = (i >> 9) % nkb;
      unsigned int gt = i / (nkb * 512u);
      unsigned int g  = gt * 16u + (ln & 15u);
      int k = (int)(kb * 32u + ((ln >> 4) * 8u) + j);
      float v;
      if (k < kinpad) v = (l == 0 && k >= 240) ? 0.0f : Wl[(size_t)g * kw + k];
      else            v = Wl[(size_t)g * kw + (k - kinpad + nin)];
      unsigned short h = f2bf(v);
      dh[i] = h; dl[i] = f2bf(v - bf2f(h));
    }
  }
  for (int l = 0; l < 3; ++l) {
    const float* Pl = Psrc[l];
    unsigned short* dh = wPh + (size_t)l * 524288u;
    unsigned short* dl = wPl + (size_t)l * 524288u;
    for (unsigned int i = gtid; i < 524288u; i += 65536u) {
      unsigned int j  = i & 7u;
      unsigned int ln = (i >> 3) & 63u;
      unsigned int kb = (i >> 9) & 31u;
      unsigned int pt = i >> 14;
      unsigned int prow = pt * 16u + (ln & 15u);
      int k = (int)(kb * 32u + ((ln >> 4) * 8u) + j);
      float v = Pl[(size_t)prow * 1024u + k];
      unsigned short h = f2bf(v);
      dh[i] = h; dl[i] = f2bf(v - bf2f(h));
    }
  }
  c_lds[tid] = 0.0f; c_lds[tid + 256] = 0.0f;

  unsigned int seq = 1;
  // one-time heavyweight coherence for init-written weights/x (then never again)
  __builtin_amdgcn_fence(__ATOMIC_RELEASE, "agent");
  gbar(bar, rel, seq++);
  __builtin_amdgcn_fence(__ATOMIC_ACQUIRE, "agent");

  // ---- fixed per-block roles ----
  const bool worker = (bid < 192);
  const int lA  = worker ? (bid >> 6) : 0;   // layer
  const int utA = bid & 63;                  // 16-unit tile (phase A)
  const int ptC = (bid & 63) >> 1;           // proj 16-col tile (phase C)
  const int mtC = bid & 1;                   // batch half (phase C)

  const int nkbA    = NKBv[lA];
  const int nkbinA  = NKBINv[lA];
  const int kinpadA = KINPADv[lA];
  const int kbwA    = nkbA >> 2;             // k-blocks per wave (6 or 8)

  for (int s = 0; s < 502; ++s) {
    const int t = s - lA;
    const bool act = worker && (t >= 0) && (t < 500);

    // ================= PHASE A: gates GEMM (waves split K) + pointwise =================
    if (act) {
      f32x4 acc[4][2];
      #pragma unroll
      for (int g = 0; g < 4; ++g) { acc[g][0] = {0.f,0.f,0.f,0.f}; acc[g][1] = {0.f,0.f,0.f,0.f}; }

      const unsigned short* wbh = wBhv[lA];
      const unsigned short* wbl = wBlv[lA];
      const int kb0 = wv * kbwA, kb1 = kb0 + kbwA;

      #pragma unroll 2
      for (int kb = kb0; kb < kb1; ++kb) {
        s16x8 fa0h, fa0l, fa1h, fa1l;
        if (kb < nkbinA) {
          if (lA == 0) {
            const unsigned short* ph = xhi + (size_t)(t * 32 + nrow) * 256 + kb * 32 + quad8;
            const unsigned short* pl = xlo + (size_t)(t * 32 + nrow) * 256 + kb * 32 + quad8;
            fa0h = *(const s16x8*)ph; fa1h = *(const s16x8*)(ph + 16 * 256);
            fa0l = *(const s16x8*)pl; fa1l = *(const s16x8*)(pl + 16 * 256);
          } else {
            const unsigned short* ph = hhi + (size_t)((lA - 1) * 32 + nrow) * 512 + kb * 32 + quad8;
            const unsigned short* pl = hlo + (size_t)((lA - 1) * 32 + nrow) * 512 + kb * 32 + quad8;
            fa0h = cload(ph); fa1h = cload(ph + 16 * 512);
            fa0l = cload(pl); fa1l = cload(pl + 16 * 512);
          }
        } else {
          const int ko = kb * 32 + quad8 - kinpadA;
          const unsigned short* ph = hhi + (size_t)(lA * 32 + nrow) * 512 + ko;
          const unsigned short* pl = hlo + (size_t)(lA * 32 + nrow) * 512 + ko;
          fa0h = cload(ph); fa1h = cload(ph + 16 * 512);
          fa0l = cload(pl); fa1l = cload(pl + 16 * 512);
        }
        #pragma unroll
        for (int g = 0; g < 4; ++g) {
          const size_t off = ((size_t)(g * 64 + utA) * nkbA + kb) * 512 + lane * 8;
          s16x8 fbh = *(const s16x8*)(wbh + off);
          s16x8 fbl = *(const s16x8*)(wbl + off);
          acc[g][0] = MFMA16(fa0h, fbh, acc[g][0]);
          acc[g][0] = MFMA16(fa0l, fbh, acc[g][0]);
          acc[g][0] = MFMA16(fa0h, fbl, acc[g][0]);
          acc[g][1] = MFMA16(fa1h, fbh, acc[g][1]);
          acc[g][1] = MFMA16(fa1l, fbh, acc[g][1]);
          acc[g][1] = MFMA16(fa1h, fbl, acc[g][1]);
        }
      }
      #pragma unroll
      for (int g = 0; g < 4; ++g) {
        #pragma unroll
        for (int r = 0; r < 4; ++r) {
          const int m0 = (lane >> 4) * 4 + r;
          exch[wv][g][m0 * 16 + (lane & 15)]        = acc[g][0][r];
          exch[wv][g][(m0 + 16) * 16 + (lane & 15)] = acc[g][1][r];
        }
      }
      __syncthreads();

      // fused pointwise: thread -> (b, 2 consecutive u); c persists in LDS
      {
        const float* bias = Bsrc[lA];
        const float* piv  = PIs[lA];
        const float* pfv  = PFs[lA];
        const float* pov  = POs[lA];
        const int b  = tid >> 3;
        const int ug = (tid & 7) * 2;
        unsigned short mh2[2], ml2[2];
        #pragma unroll
        for (int j = 0; j < 2; ++j) {
          const int u = ug + j, e = b * 16 + u;
          const int uc = utA * 16 + u;
          const float cin = exch[0][0][e] + exch[1][0][e] + exch[2][0][e] + exch[3][0][e] + bias[uc];
          const float gi  = exch[0][1][e] + exch[1][1][e] + exch[2][1][e] + exch[3][1][e] + bias[1024 + uc];
          const float gf  = exch[0][2][e] + exch[1][2][e] + exch[2][2][e] + exch[3][2][e] + bias[2048 + uc];
          const float go  = exch[0][3][e] + exch[1][3][e] + exch[2][3][e] + exch[3][3][e] + bias[3072 + uc];
          const float cx  = c_lds[e];
          const float ig  = fsig(gi + piv[uc] * cx);
          const float fg  = fsig(gf + pfv[uc] * cx);
          float cy = fg * cx + ig * ftanh(cin);
          cy = fminf(50.0f, fmaxf(-50.0f, cy));
          const float og = fsig(go + pov[uc] * cy);
          const float mv = og * ftanh(cy);
          c_lds[e] = cy;
          mh2[j] = f2bf(mv);
          ml2[j] = f2bf(mv - bf2f(mh2[j]));
        }
        const size_t mi = (size_t)(lA * 32 + b) * 1024 + utA * 16 + ug;
        cstore2(mhi + mi, mh2[0], mh2[1]);
        cstore2(mlo + mi, ml2[0], ml2[1]);
      }
    }
    gbar(bar, rel, seq++);

    // ================= PHASE C: projection (waves split K) + h/out write =================
    if (act) {
      const unsigned short* pph = wPh + (size_t)lA * 524288 + ((size_t)ptC * 32) * 512 + lane * 8;
      const unsigned short* ppl = wPl + (size_t)lA * 524288 + ((size_t)ptC * 32) * 512 + lane * 8;
      const unsigned short* mah = mhi + (size_t)(lA * 32 + mtC * 16 + nrow) * 1024;
      const unsigned short* mal = mlo + (size_t)(lA * 32 + mtC * 16 + nrow) * 1024;
      f32x4 acc = {0.f, 0.f, 0.f, 0.f};
      #pragma unroll 2
      for (int kb = wv * 8; kb < wv * 8 + 8; ++kb) {
        const int ko = kb * 32 + quad8;
        s16x8 fah = cload(mah + ko);
        s16x8 fal = cload(mal + ko);
        s16x8 fbh = *(const s16x8*)(pph + (size_t)kb * 512);
        s16x8 fbl = *(const s16x8*)(ppl + (size_t)kb * 512);
        acc = MFMA16(fah, fbh, acc);
        acc = MFMA16(fal, fbh, acc);
        acc = MFMA16(fah, fbl, acc);
      }
      #pragma unroll
      for (int r = 0; r < 4; ++r) {
        exch[wv][0][((lane >> 4) * 4 + r) * 16 + (lane & 15)] = acc[r];
      }
      __syncthreads();
      if (tid < 128) {
        const int r  = tid >> 3;           // 0..15 batch row within half
        const int pg = (tid & 7) * 2;      // even proj col
        const int e0 = r * 16 + pg;
        const float v0 = exch[0][0][e0]     + exch[1][0][e0]     + exch[2][0][e0]     + exch[3][0][e0];
        const float v1 = exch[0][0][e0 + 1] + exch[1][0][e0 + 1] + exch[2][0][e0 + 1] + exch[3][0][e0 + 1];
        const int b = mtC * 16 + r;
        const int p = ptC * 16 + pg;
        const size_t hidx = (size_t)(lA * 32 + b) * 512 + p;
        const unsigned short h0 = f2bf(v0), h1 = f2bf(v1);
        cstore2(hhi + hidx, h0, h1);
        cstore2(hlo + hidx, f2bf(v0 - bf2f(h0)), f2bf(v1 - bf2f(h1)));
        if (lA == 2) {
          out[((size_t)t * 32 + b) * 512 + p]     = v0;
          out[((size_t)t * 32 + b) * 512 + p + 1] = v1;
        }
      }
    }
    gbar(bar, rel, seq++);
  }
}

extern "C" void kernel_launch(void* const* d_in, const int* in_sizes, int n_in,
                              void* d_out, int out_size, void* d_ws, size_t ws_size,
                              hipStream_t stream) {
  const float* x   = (const float*)d_in[0];
  const float* W0  = (const float*)d_in[1];
  const float* b0  = (const float*)d_in[2];
  const float* P0  = (const float*)d_in[3];
  const float* pi0 = (const float*)d_in[4];
  const float* pf0 = (const float*)d_in[5];
  const float* po0 = (const float*)d_in[6];
  const float* W1  = (const float*)d_in[7];
  const float* b1  = (const float*)d_in[8];
  const float* P1  = (const float*)d_in[9];
  const float* pi1 = (const float*)d_in[10];
  const float* pf1 = (const float*)d_in[11];
  const float* po1 = (const float*)d_in[12];
  const float* W2  = (const float*)d_in[13];
  const float* b2  = (const float*)d_in[14];
  const float* P2  = (const float*)d_in[15];
  const float* pi2 = (const float*)d_in[16];
  const float* pf2 = (const float*)d_in[17];
  const float* po2 = (const float*)d_in[18];

  hipLaunchKernelGGL(lstmp_persist, dim3(256), dim3(256), 0, stream,
                     x, W0, b0, P0, pi0, pf0, po0,
                     W1, b1, P1, pi1, pf1, po1,
                     W2, b2, P2, pi2, pf2, po2,
                     (float*)d_out, (unsigned char*)d_ws);
}

// Round 4
// 11036.980 us; speedup vs baseline: 2.8211x; 1.1543x over previous
//
#include <hip/hip_runtime.h>

// Persistent wavefront-pipelined LSTMP (3 layers), split-bf16 MFMA emulating fp32.
// Round 4: 512-thread blocks (8 waves, 2x MLP), grid=192 (all workers, 1 block/CU
// via LDS pad); ONE global barrier per step (h parity double-buffered) + per-producer
// m-flags for the A->C exchange; proj weights preloaded before the flag poll.
// Exchange data (h/m) still moves via relaxed agent-scope atomics (LIC-coherent).

typedef short s16x4 __attribute__((ext_vector_type(4)));
typedef short s16x8 __attribute__((ext_vector_type(8)));
typedef float f32x4 __attribute__((ext_vector_type(4)));

#define MFMA16(a,b,c) __builtin_amdgcn_mfma_f32_16x16x32_bf16((a),(b),(c),0,0,0)

__device__ __forceinline__ unsigned short f2bf(float f) {
  unsigned int u = __builtin_bit_cast(unsigned int, f);
  u += 0x7FFFu + ((u >> 16) & 1u);          // RNE
  return (unsigned short)(u >> 16);
}
__device__ __forceinline__ float bf2f(unsigned short h) {
  unsigned int u = ((unsigned int)h) << 16;
  return __builtin_bit_cast(float, u);
}
__device__ __forceinline__ float fsig(float x)  { return __fdividef(1.0f, 1.0f + __expf(-x)); }
__device__ __forceinline__ float ftanh(float x) { return 1.0f - __fdividef(2.0f, 1.0f + __expf(2.0f * x)); }

// Coherent (LIC) 16B read as two relaxed agent-scope 8B atomic loads.
__device__ __forceinline__ s16x8 cload(const unsigned short* p) {
  unsigned long long a = __hip_atomic_load((unsigned long long*)p,       __ATOMIC_RELAXED, __HIP_MEMORY_SCOPE_AGENT);
  unsigned long long b = __hip_atomic_load((unsigned long long*)(p + 4), __ATOMIC_RELAXED, __HIP_MEMORY_SCOPE_AGENT);
  s16x4 x = __builtin_bit_cast(s16x4, a);
  s16x4 y = __builtin_bit_cast(s16x4, b);
  s16x8 r = {x[0], x[1], x[2], x[3], y[0], y[1], y[2], y[3]};
  return r;
}
__device__ __forceinline__ void cstore1(unsigned short* p, unsigned short v) {
  __hip_atomic_store(p, v, __ATOMIC_RELAXED, __HIP_MEMORY_SCOPE_AGENT);
}

// Relaxed sense-counting grid barrier (192 blocks, 512 threads).
__device__ __forceinline__ void gbar(unsigned int* bar, unsigned int* rel, unsigned int seq) {
  __syncthreads();
  asm volatile("" ::: "memory");
  if (blockIdx.x == 0) {
    const int tid = threadIdx.x;
    if (tid > 0 && tid < 192) {
      while (__hip_atomic_load(&bar[tid * 16], __ATOMIC_RELAXED, __HIP_MEMORY_SCOPE_AGENT) != seq) {
        __builtin_amdgcn_s_sleep(1);
      }
    }
    __syncthreads();
    if (tid == 0) {
      __hip_atomic_store(rel, seq, __ATOMIC_RELAXED, __HIP_MEMORY_SCOPE_AGENT);
    }
  } else {
    if (threadIdx.x == 0) {
      __hip_atomic_store(&bar[blockIdx.x * 16], seq, __ATOMIC_RELAXED, __HIP_MEMORY_SCOPE_AGENT);
      while (__hip_atomic_load(rel, __ATOMIC_RELAXED, __HIP_MEMORY_SCOPE_AGENT) != seq) {
        __builtin_amdgcn_s_sleep(1);
      }
    }
    __syncthreads();
  }
  asm volatile("" ::: "memory");
}

__global__ __launch_bounds__(512) void lstmp_persist(
    const float* __restrict__ x,
    const float* __restrict__ W0, const float* __restrict__ b0, const float* __restrict__ P0,
    const float* __restrict__ pi0, const float* __restrict__ pf0, const float* __restrict__ po0,
    const float* __restrict__ W1, const float* __restrict__ b1, const float* __restrict__ P1,
    const float* __restrict__ pi1, const float* __restrict__ pf1, const float* __restrict__ po1,
    const float* __restrict__ W2, const float* __restrict__ b2, const float* __restrict__ P2,
    const float* __restrict__ pi2, const float* __restrict__ pf2, const float* __restrict__ po2,
    float* __restrict__ out, unsigned char* __restrict__ ws)
{
  const int tid  = threadIdx.x;
  const int bid  = blockIdx.x;
  const int lane = tid & 63;
  const int wv   = tid >> 6;             // 0..7
  const int quad8 = (lane >> 4) * 8;
  const int nrow  = lane & 15;

  // ---- workspace carve ----
  unsigned int* bar   = (unsigned int*)ws;   // 192 slots * 16 uints (within 4096)
  unsigned int* rel   = bar + 4096;
  unsigned int* mflag = rel + 16;            // 3*64 flags
  unsigned short* xhi = (unsigned short*)(ws + 20480);
  unsigned short* xlo  = xhi  + 4096000;   // 500*32*256
  unsigned short* hhi  = xlo  + 4096000;   // 2 bufs * 3*32*512
  unsigned short* hlo  = hhi  + 98304;
  unsigned short* mhi  = hlo  + 98304;     // 3*32*1024
  unsigned short* mlo  = mhi  + 98304;
  unsigned short* wBh0 = mlo  + 98304;     // 256*24*512
  unsigned short* wBl0 = wBh0 + 3145728;
  unsigned short* wBh1 = wBl0 + 3145728;   // 256*32*512
  unsigned short* wBl1 = wBh1 + 4194304;
  unsigned short* wBh2 = wBl1 + 4194304;
  unsigned short* wBl2 = wBh2 + 4194304;
  unsigned short* wPh  = wBl2 + 4194304;   // 3 * 32*32*512
  unsigned short* wPl  = wPh  + 1572864;

  const float* Wsrc[3] = {W0, W1, W2};
  const float* Psrc[3] = {P0, P1, P2};
  const float* Bsrc[3] = {b0, b1, b2};
  const float* PIs[3]  = {pi0, pi1, pi2};
  const float* PFs[3]  = {pf0, pf1, pf2};
  const float* POs[3]  = {po0, po1, po2};
  unsigned short* wBhv[3] = {wBh0, wBh1, wBh2};
  unsigned short* wBlv[3] = {wBl0, wBl1, wBl2};
  const int NKBv[3]    = {24, 32, 32};
  const int NKBINv[3]  = {8, 16, 16};
  const int KINPADv[3] = {256, 512, 512};
  const int KWv[3]     = {752, 1024, 1024};
  const int NINv[3]    = {240, 512, 512};

  __shared__ float exch[8][4][512];  // 64 KB: per-wave partial sums
  __shared__ float c_lds[512];       // persistent cell state
  __shared__ float lds_pad[4096];    // 16 KB pad -> 82 KB total -> 1 block/CU
  ((volatile float*)lds_pad)[tid & 4095] = 0.0f;  // keep it allocated

  const unsigned int NT = 192u * 512u;
  const unsigned int gtid = (unsigned int)bid * 512u + (unsigned int)tid;

  // ================= INIT =================
  for (unsigned int i = gtid; i < 4096000u; i += NT) {
    unsigned int k = i & 255u, tb = i >> 8;
    float v = (k < 240u) ? x[tb * 240u + k] : 0.0f;
    unsigned short h = f2bf(v);
    xhi[i] = h; xlo[i] = f2bf(v - bf2f(h));
  }
  for (unsigned int i = gtid; i < 98304u; i += NT) { hhi[i] = 0; hlo[i] = 0; }
  for (int l = 0; l < 3; ++l) {
    const unsigned int nkb = (unsigned int)NKBv[l];
    const unsigned int tot = 256u * nkb * 512u;
    const float* Wl = Wsrc[l];
    unsigned short* dh = wBhv[l];
    unsigned short* dl = wBlv[l];
    const int kinpad = KINPADv[l], kw = KWv[l], nin = NINv[l];
    for (unsigned int i = gtid; i < tot; i += NT) {
      unsigned int j  = i & 7u;
      unsigned int ln = (i >> 3) & 63u;
      unsigned int kb = (i >> 9) % nkb;
      unsigned int gt = i / (nkb * 512u);
      unsigned int g  = gt * 16u + (ln & 15u);
      int k = (int)(kb * 32u + ((ln >> 4) * 8u) + j);
      float v;
      if (k < kinpad) v = (l == 0 && k >= 240) ? 0.0f : Wl[(size_t)g * kw + k];
      else            v = Wl[(size_t)g * kw + (k - kinpad + nin)];
      unsigned short h = f2bf(v);
      dh[i] = h; dl[i] = f2bf(v - bf2f(h));
    }
  }
  for (int l = 0; l < 3; ++l) {
    const float* Pl = Psrc[l];
    unsigned short* dh = wPh + (size_t)l * 524288u;
    unsigned short* dl = wPl + (size_t)l * 524288u;
    for (unsigned int i = gtid; i < 524288u; i += NT) {
      unsigned int j  = i & 7u;
      unsigned int ln = (i >> 3) & 63u;
      unsigned int kb = (i >> 9) & 31u;
      unsigned int pt = i >> 14;
      unsigned int prow = pt * 16u + (ln & 15u);
      int k = (int)(kb * 32u + ((ln >> 4) * 8u) + j);
      float v = Pl[(size_t)prow * 1024u + k];
      unsigned short h = f2bf(v);
      dh[i] = h; dl[i] = f2bf(v - bf2f(h));
    }
  }
  if (tid < 512) c_lds[tid] = 0.0f;

  unsigned int seq = 1;
  __builtin_amdgcn_fence(__ATOMIC_RELEASE, "agent");
  gbar(bar, rel, seq++);
  __builtin_amdgcn_fence(__ATOMIC_ACQUIRE, "agent");

  // ---- fixed per-block roles (grid = 192, all workers) ----
  const int lA  = bid >> 6;          // layer 0..2
  const int utA = bid & 63;          // 16-unit tile (phase A)
  const int ptC = (bid & 63) >> 1;   // proj 16-col tile (phase C)
  const int mtC = bid & 1;           // batch half (phase C)

  const int nkbA    = NKBv[lA];
  const int nkbinA  = NKBINv[lA];
  const int kinpadA = KINPADv[lA];
  const int kbwA    = nkbA >> 3;     // k-blocks per wave: 3 or 4

  for (int s = 0; s < 502; ++s) {
    const int t = s - lA;
    const bool act = (t >= 0) && (t < 500);
    const int rbuf = (s + 1) & 1;    // h buffer written at step s-1
    const int wbuf = s & 1;          // h buffer written at step s

    if (act) {
      // ============ PHASE A: gates GEMM (8 waves split K) ============
      f32x4 acc[4][2];
      #pragma unroll
      for (int g = 0; g < 4; ++g) { acc[g][0] = {0.f,0.f,0.f,0.f}; acc[g][1] = {0.f,0.f,0.f,0.f}; }

      const unsigned short* wbh = wBhv[lA];
      const unsigned short* wbl = wBlv[lA];
      const unsigned short* hbh = hhi + rbuf * 49152;
      const unsigned short* hbl = hlo + rbuf * 49152;
      const int kb0 = wv * kbwA, kb1 = kb0 + kbwA;

      #pragma unroll 2
      for (int kb = kb0; kb < kb1; ++kb) {
        s16x8 fa0h, fa0l, fa1h, fa1l;
        if (kb < nkbinA) {
          if (lA == 0) {
            const unsigned short* ph = xhi + (size_t)(t * 32 + nrow) * 256 + kb * 32 + quad8;
            const unsigned short* pl = xlo + (size_t)(t * 32 + nrow) * 256 + kb * 32 + quad8;
            fa0h = *(const s16x8*)ph; fa1h = *(const s16x8*)(ph + 16 * 256);
            fa0l = *(const s16x8*)pl; fa1l = *(const s16x8*)(pl + 16 * 256);
          } else {
            const unsigned short* ph = hbh + (size_t)((lA - 1) * 32 + nrow) * 512 + kb * 32 + quad8;
            const unsigned short* pl = hbl + (size_t)((lA - 1) * 32 + nrow) * 512 + kb * 32 + quad8;
            fa0h = cload(ph); fa1h = cload(ph + 16 * 512);
            fa0l = cload(pl); fa1l = cload(pl + 16 * 512);
          }
        } else {
          const int ko = kb * 32 + quad8 - kinpadA;
          const unsigned short* ph = hbh + (size_t)(lA * 32 + nrow) * 512 + ko;
          const unsigned short* pl = hbl + (size_t)(lA * 32 + nrow) * 512 + ko;
          fa0h = cload(ph); fa1h = cload(ph + 16 * 512);
          fa0l = cload(pl); fa1l = cload(pl + 16 * 512);
        }
        #pragma unroll
        for (int g = 0; g < 4; ++g) {
          const size_t off = ((size_t)(g * 64 + utA) * nkbA + kb) * 512 + lane * 8;
          s16x8 fbh = *(const s16x8*)(wbh + off);
          s16x8 fbl = *(const s16x8*)(wbl + off);
          acc[g][0] = MFMA16(fa0h, fbh, acc[g][0]);
          acc[g][0] = MFMA16(fa0l, fbh, acc[g][0]);
          acc[g][0] = MFMA16(fa0h, fbl, acc[g][0]);
          acc[g][1] = MFMA16(fa1h, fbh, acc[g][1]);
          acc[g][1] = MFMA16(fa1l, fbh, acc[g][1]);
          acc[g][1] = MFMA16(fa1h, fbl, acc[g][1]);
        }
      }
      #pragma unroll
      for (int g = 0; g < 4; ++g) {
        #pragma unroll
        for (int r = 0; r < 4; ++r) {
          const int m0 = (lane >> 4) * 4 + r;
          exch[wv][g][m0 * 16 + (lane & 15)]        = acc[g][0][r];
          exch[wv][g][(m0 + 16) * 16 + (lane & 15)] = acc[g][1][r];
        }
      }
      __syncthreads();

      // ---- fused pointwise: 512 threads, 1 (b,u) each ----
      {
        const float* bias = Bsrc[lA];
        const float* piv  = PIs[lA];
        const float* pfv  = PFs[lA];
        const float* pov  = POs[lA];
        const int e = tid, b = tid >> 4, u = tid & 15;
        const int uc = utA * 16 + u;
        float sc = 0.f, si = 0.f, sf = 0.f, so = 0.f;
        #pragma unroll
        for (int w = 0; w < 8; ++w) {
          sc += exch[w][0][e]; si += exch[w][1][e];
          sf += exch[w][2][e]; so += exch[w][3][e];
        }
        const float cin = sc + bias[uc];
        const float gi  = si + bias[1024 + uc];
        const float gf  = sf + bias[2048 + uc];
        const float go  = so + bias[3072 + uc];
        const float cx  = c_lds[e];
        const float ig  = fsig(gi + piv[uc] * cx);
        const float fg  = fsig(gf + pfv[uc] * cx);
        float cy = fg * cx + ig * ftanh(cin);
        cy = fminf(50.0f, fmaxf(-50.0f, cy));
        const float og = fsig(go + pov[uc] * cy);
        const float mv = og * ftanh(cy);
        c_lds[e] = cy;
        const unsigned short mh = f2bf(mv);
        const size_t mi = (size_t)(lA * 32 + b) * 1024 + uc;
        cstore1(mhi + mi, mh);
        cstore1(mlo + mi, f2bf(mv - bf2f(mh)));
      }
      __syncthreads();   // drains each wave's vm stores before flag
      if (tid == 0) {
        __hip_atomic_store(&mflag[lA * 64 + utA], (unsigned int)(s + 1),
                           __ATOMIC_RELAXED, __HIP_MEMORY_SCOPE_AGENT);
      }

      // ============ PHASE C: projection (8 waves split K=32kb) ============
      // preload proj weight frags (independent of m) before the poll
      const unsigned short* pph = wPh + (size_t)lA * 524288 + ((size_t)ptC * 32) * 512 + lane * 8;
      const unsigned short* ppl = wPl + (size_t)lA * 524288 + ((size_t)ptC * 32) * 512 + lane * 8;
      s16x8 pbh[4], pbl[4];
      #pragma unroll
      for (int j = 0; j < 4; ++j) {
        const int kb = wv * 4 + j;
        pbh[j] = *(const s16x8*)(pph + (size_t)kb * 512);
        pbl[j] = *(const s16x8*)(ppl + (size_t)kb * 512);
      }
      // wait for all 64 m-producers of this layer
      if (wv == 0) {
        const unsigned int want = (unsigned int)(s + 1);
        const unsigned int* fp = mflag + lA * 64 + lane;
        while (__hip_atomic_load(fp, __ATOMIC_RELAXED, __HIP_MEMORY_SCOPE_AGENT) != want) {
          __builtin_amdgcn_s_sleep(1);
        }
      }
      __syncthreads();

      const unsigned short* mah = mhi + (size_t)(lA * 32 + mtC * 16 + nrow) * 1024;
      const unsigned short* mal = mlo + (size_t)(lA * 32 + mtC * 16 + nrow) * 1024;
      f32x4 pacc = {0.f, 0.f, 0.f, 0.f};
      #pragma unroll
      for (int j = 0; j < 4; ++j) {
        const int ko = (wv * 4 + j) * 32 + quad8;
        s16x8 fah = cload(mah + ko);
        s16x8 fal = cload(mal + ko);
        pacc = MFMA16(fah, pbh[j], pacc);
        pacc = MFMA16(fal, pbh[j], pacc);
        pacc = MFMA16(fah, pbl[j], pacc);
      }
      #pragma unroll
      for (int r = 0; r < 4; ++r) {
        exch[wv][0][((lane >> 4) * 4 + r) * 16 + (lane & 15)] = pacc[r];
      }
      __syncthreads();
      if (tid < 256) {
        float v = 0.f;
        #pragma unroll
        for (int w = 0; w < 8; ++w) v += exch[w][0][tid];
        const int b = mtC * 16 + (tid >> 4);
        const int p = ptC * 16 + (tid & 15);
        const size_t hidx = (size_t)wbuf * 49152 + (size_t)(lA * 32 + b) * 512 + p;
        const unsigned short hh = f2bf(v);
        cstore1(hhi + hidx, hh);
        cstore1(hlo + hidx, f2bf(v - bf2f(hh)));
        if (lA == 2) out[((size_t)t * 32 + b) * 512 + p] = v;
      }
    }
    gbar(bar, rel, seq++);
  }
}

extern "C" void kernel_launch(void* const* d_in, const int* in_sizes, int n_in,
                              void* d_out, int out_size, void* d_ws, size_t ws_size,
                              hipStream_t stream) {
  const float* x   = (const float*)d_in[0];
  const float* W0  = (const float*)d_in[1];
  const float* b0  = (const float*)d_in[2];
  const float* P0  = (const float*)d_in[3];
  const float* pi0 = (const float*)d_in[4];
  const float* pf0 = (const float*)d_in[5];
  const float* po0 = (const float*)d_in[6];
  const float* W1  = (const float*)d_in[7];
  const float* b1  = (const float*)d_in[8];
  const float* P1  = (const float*)d_in[9];
  const float* pi1 = (const float*)d_in[10];
  const float* pf1 = (const float*)d_in[11];
  const float* po1 = (const float*)d_in[12];
  const float* W2  = (const float*)d_in[13];
  const float* b2  = (const float*)d_in[14];
  const float* P2  = (const float*)d_in[15];
  const float* pi2 = (const float*)d_in[16];
  const float* pf2 = (const float*)d_in[17];
  const float* po2 = (const float*)d_in[18];

  hipLaunchKernelGGL(lstmp_persist, dim3(192), dim3(512), 0, stream,
                     x, W0, b0, P0, pi0, pf0, po0,
                     W1, b1, P1, pi1, pf1, po1,
                     W2, b2, P2, pi2, pf2, po2,
                     (float*)d_out, (unsigned char*)d_ws);
}